// Round 1
// baseline (174.820 us; speedup 1.0000x reference)
//
#include <hip/hip_runtime.h>
#include <math.h>

// CTC forward loss, Keras ctc_batch_cost semantics.
// B=1024, T=256, C=128, L=64, S=2L+1=129, blank=C-1=127.
#define BATCH 1024
#define TT    256
#define CC    128
#define LL    64
#define SSTATES 129
#define BLANK 127
#define NEGV  (-1e30f)
#define EPSV  (1e-7f)

__device__ __forceinline__ float lae(float a, float b) {
    // logaddexp(a, b) = max + log(1 + exp(min - max))
    float m = fmaxf(a, b);
    float d = fminf(a, b) - m;          // <= 0
    return m + __logf(1.0f + __expf(d));
}

__global__ __launch_bounds__(256) void ctc_fwd_kernel(const int* __restrict__ y_true,
                                                      const float* __restrict__ y_pred,
                                                      float* __restrict__ out) {
    const int b   = blockIdx.x;
    const int tid = threadIdx.x;

    __shared__ float p_sh[2][CC];        // raw probs + eps, double-buffered
    __shared__ float red_sh[2][2];       // per-wave partial sums
    __shared__ float alpha_sh[2][SSTATES];
    __shared__ int   ext_sh[SSTATES];    // extended label per state
    __shared__ unsigned char skip_sh[SSTATES];

    const float* yp = y_pred + (size_t)b * (TT * CC);
    const int*   yt = y_true + b * LL;

    // Build extended sequence: ext[2i]=blank, ext[2i+1]=y_true[i].
    // allow_skip[s] iff s odd, s>=3, y_true[(s-1)/2] != y_true[(s-1)/2 - 1].
    if (tid < SSTATES) {
        int lbl = (tid & 1) ? yt[tid >> 1] : BLANK;
        ext_sh[tid] = lbl;
        unsigned char allow = 0;
        if ((tid & 1) && tid >= 3) {
            allow = (yt[tid >> 1] != yt[(tid >> 1) - 1]) ? (unsigned char)1 : (unsigned char)0;
        }
        skip_sh[tid] = allow;
    }

    // Prefetch t=0 row.
    float pnext = 0.0f;
    if (tid < CC) pnext = yp[tid];

    int cb = 0;
    for (int t = 0; t < TT; ++t, cb ^= 1) {
        // ---- phase 1: stage probs for step t, reduce row sum, prefetch t+1 ----
        float pc = pnext + EPSV;
        if (tid < CC && (t + 1) < TT) pnext = yp[(size_t)(t + 1) * CC + tid];
        if (tid < CC) {
            p_sh[cb][tid] = pc;
            float s = pc;
            #pragma unroll
            for (int off = 32; off >= 1; off >>= 1) s += __shfl_xor(s, off);
            if ((tid & 63) == 0) red_sh[cb][tid >> 6] = s;
        }
        __syncthreads();
        // ---- phase 3: DP update ----
        if (tid < SSTATES) {
            float lse   = __logf(red_sh[cb][0] + red_sh[cb][1]);
            float lpext = __logf(p_sh[cb][ext_sh[tid]]) - lse;
            float anew;
            if (t == 0) {
                anew = (tid < 2) ? lpext : NEGV;
            } else {
                const float* ap = alpha_sh[cb ^ 1];
                float a   = ap[tid];
                float p1  = (tid >= 1) ? ap[tid - 1] : NEGV;
                float acc = lae(a, p1);
                if (skip_sh[tid]) acc = lae(acc, ap[tid - 2]);
                anew = acc + lpext;
            }
            alpha_sh[cb][tid] = anew;
        }
        // Single barrier per step: iteration t+1's barrier separates
        // phase3(t) from phase3(t+1); all LDS buffer reuse is 2 phases apart.
    }
    __syncthreads();

    if (tid == 0) {
        const float* af = alpha_sh[(TT - 1) & 1];
        out[b] = -lae(af[SSTATES - 1], af[SSTATES - 2]);
    }
}

extern "C" void kernel_launch(void* const* d_in, const int* in_sizes, int n_in,
                              void* d_out, int out_size, void* d_ws, size_t ws_size,
                              hipStream_t stream) {
    const int*   y_true = (const int*)d_in[0];
    const float* y_pred = (const float*)d_in[1];
    float*       out    = (float*)d_out;
    ctc_fwd_kernel<<<BATCH, 256, 0, stream>>>(y_true, y_pred, out);
}

// Round 2
// 55.346 us; speedup vs baseline: 3.1586x; 3.1586x over previous
//
#include <hip/hip_runtime.h>
#include <math.h>

// CTC forward loss, Keras ctc_batch_cost semantics.
// B=1024, T=256, C=128, L=64, S=2L+1=129, blank=C-1=127.
// Strategy: prob-domain forward DP (no per-step transcendentals) with
// power-of-2 rescaling every 8 steps; single wave runs the DP with states
// in registers (2 states/lane + state 128 on lane 0); pre-pass builds an
// fp16 table of the 65 needed probs per row + sum of log(row sums).
#define BATCH 1024
#define TT    256
#define CC    128
#define LL    64
#define BLANK 127
#define EPSV  (1e-7f)

typedef _Float16 half_t;

__global__ __launch_bounds__(256) void ctc_fwd_kernel(const int* __restrict__ y_true,
                                                      const float* __restrict__ y_pred,
                                                      float* __restrict__ out) {
    __shared__ half_t qtab[TT][66];            // q[t][label slot l] = p[t][yt[l]]+eps (fp16)
    __shared__ float  qblank[TT];              // q[t][blank] (f32)
    __shared__ __align__(16) float stage[4][CC]; // per-wave row staging
    __shared__ float  logZpart[4];
    __shared__ int    labels[LL];

    const int b    = blockIdx.x;
    const int tid  = threadIdx.x;
    const int wv   = tid >> 6;
    const int lane = tid & 63;

    const float* yp = y_pred + (size_t)b * (TT * CC);

    if (tid < LL) labels[tid] = y_true[b * LL + tid];
    __syncthreads();

    const int lab = labels[lane];

    // ---------------- Phase A: stream y_pred, build qtab/qblank/logZ ----------------
    // Wave w handles rows t = w, w+4, ..., w+252. Coalesced float2 per lane.
    float zacc = 0.0f;
    float2 v = ((const float2*)(yp + (size_t)wv * CC))[lane];
    for (int k = 0; k < TT / 4; ++k) {
        const int t = wv + 4 * k;
        float2 vn = v;
        if (k + 1 < TT / 4) vn = ((const float2*)(yp + (size_t)(t + 4) * CC))[lane];
        float q0 = v.x + EPSV, q1 = v.y + EPSV;
        ((float2*)&stage[wv][2 * lane])[0] = make_float2(q0, q1);
        float s = q0 + q1;
        #pragma unroll
        for (int off = 1; off < 64; off <<= 1) s += __shfl_xor(s, off);
        zacc += __logf(s);
        // gather this row's needed probs (wave-synchronous; compiler inserts lgkmcnt)
        float ql = stage[wv][lab];
        qtab[t][lane] = (half_t)ql;
        if (lane == 0) qblank[t] = stage[wv][BLANK];
        v = vn;
    }
    if (lane == 0) logZpart[wv] = zacc;
    __syncthreads();

    // ---------------- Phase B: single-wave register DP ----------------
    if (wv == 0) {
        const float logZ = logZpart[0] + logZpart[1] + logZpart[2] + logZpart[3];
        const int   labm1 = labels[(lane + 63) & 63];
        const float mskip = (lane >= 1 && lab != labm1) ? 1.0f : 0.0f;
        const bool  l0 = (lane == 0);
        const int   src = (lane + 63) & 63;

        // t = 0 init: alpha[0]=q0[blank], alpha[1]=q0[yt[0]], rest 0.
        float ql0 = (float)qtab[0][lane];
        float a0 = l0 ? qblank[0] : 0.0f;   // even state 2*lane
        float a1 = l0 ? ql0       : 0.0f;   // odd state 2*lane+1
        float aX = 0.0f;                    // state 128 (lane 0 only)
        int Esum = 0;

        #pragma unroll 8
        for (int t = 1; t < TT; ++t) {
            float nb = __shfl(a1, src);     // alpha[2*lane-1]; lane0 gets alpha[127]
            float qb = qblank[t];
            float ql = (float)qtab[t][lane];
            float nb0 = l0 ? 0.0f : nb;
            float na0 = (a0 + nb0) * qb;                    // blank state: no skip
            float na1 = fmaf(mskip, nb, a0 + a1) * ql;      // label state: optional skip
            aX = l0 ? (aX + nb) * qb : 0.0f;                // state 128 (blank)
            a0 = na0; a1 = na1;
            if ((t & 7) == 7) {                             // power-of-2 rescale
                float m = fmaxf(a0, a1);
                m = fmaxf(m, l0 ? aX : 0.0f);
                #pragma unroll
                for (int off = 1; off < 64; off <<= 1) m = fmaxf(m, __shfl_xor(m, off));
                int ex = (int)((__float_as_uint(m) >> 23) & 0xFF);
                int e  = 127 - ex;
                float sc = __uint_as_float((unsigned)(127 + e) << 23);
                a0 *= sc; a1 *= sc; aX *= sc;
                Esum += e;
            }
        }
        float a127 = __shfl(a1, 63);
        if (lane == 0) {
            float tot = aX + a127;          // alpha[128] + alpha[127]
            out[b] = logZ + (float)Esum * 0.69314718055994531f - __logf(tot);
        }
    }
}

extern "C" void kernel_launch(void* const* d_in, const int* in_sizes, int n_in,
                              void* d_out, int out_size, void* d_ws, size_t ws_size,
                              hipStream_t stream) {
    const int*   y_true = (const int*)d_in[0];
    const float* y_pred = (const float*)d_in[1];
    float*       out    = (float*)d_out;
    ctc_fwd_kernel<<<BATCH, 256, 0, stream>>>(y_true, y_pred, out);
}

// Round 3
// 54.738 us; speedup vs baseline: 3.1938x; 1.0111x over previous
//
#include <hip/hip_runtime.h>
#include <math.h>

// CTC forward loss, Keras ctc_batch_cost semantics.
// B=1024, T=256, C=128, L=64, S=2L+1=129, blank=C-1=127.
// Prob-domain forward DP (no per-step transcendentals) with power-of-2
// rescaling every 8 steps. Phase A: 4 waves stream y_pred (registers only:
// row sum via shfl reduce, label gather via 2 shfls), build fp16 q-table.
// Phase B: single wave runs the DP with states in registers.
#define BATCH 1024
#define TT    256
#define CC    128
#define LL    64
#define BLANK 127
#define EPSV  (1e-7f)

typedef _Float16 half_t;

__global__ __launch_bounds__(256) void ctc_fwd_kernel(const int* __restrict__ y_true,
                                                      const float* __restrict__ y_pred,
                                                      float* __restrict__ out) {
    __shared__ half_t qtab[TT][66];   // q[t][label slot l] = p[t][yt[l]]+eps
    __shared__ float  qblank[TT];     // q[t][blank]
    __shared__ float  logZpart[4];
    __shared__ int    labels[LL];

    const int b    = blockIdx.x;
    const int tid  = threadIdx.x;
    const int wv   = tid >> 6;
    const int lane = tid & 63;

    const float* yp = y_pred + (size_t)b * (TT * CC);

    if (tid < LL) labels[tid] = y_true[b * LL + tid];
    __syncthreads();

    const int lab  = labels[lane];
    const int srcl = lab >> 1;

    // ---------------- Phase A: stream y_pred, build qtab/qblank/logZ ----------------
    // Wave w handles rows t = w + 4*i, i=0..63; unroll 4 (group of 16 k-iters),
    // 4 loads in flight, 4 independent reduce chains.
    float zacc = 0.0f;
    float2 v[4];
    #pragma unroll
    for (int j = 0; j < 4; ++j)
        v[j] = ((const float2*)(yp + (size_t)(wv + 4 * j) * CC))[lane];

    for (int k = 0; k < 16; ++k) {
        float2 vn[4];
        if (k < 15) {
            #pragma unroll
            for (int j = 0; j < 4; ++j)
                vn[j] = ((const float2*)(yp + (size_t)(wv + 16 * (k + 1) + 4 * j) * CC))[lane];
        }
        #pragma unroll
        for (int j = 0; j < 4; ++j) {
            const int t = wv + 16 * k + 4 * j;
            float q0 = v[j].x + EPSV, q1 = v[j].y + EPSV;
            float s = q0 + q1;
            #pragma unroll
            for (int off = 1; off < 64; off <<= 1) s += __shfl_xor(s, off);
            zacc += __logf(s);
            // label gather from registers: col 2*srcl = v.x of lane srcl, col 2*srcl+1 = v.y
            float ga = __shfl(q0, srcl);
            float gb = __shfl(q1, srcl);
            qtab[t][lane] = (half_t)((lab & 1) ? gb : ga);
            if (lane == 63) qblank[t] = q1;   // col 127 == blank
        }
        #pragma unroll
        for (int j = 0; j < 4; ++j) v[j] = vn[j];
    }
    if (lane == 0) logZpart[wv] = zacc;
    __syncthreads();

    // ---------------- Phase B: single-wave register DP ----------------
    if (wv == 0) {
        const float logZ = logZpart[0] + logZpart[1] + logZpart[2] + logZpart[3];
        const int   labm1 = labels[(lane + 63) & 63];
        const float mskip = (lane >= 1 && lab != labm1) ? 1.0f : 0.0f;
        const bool  l0  = (lane == 0);
        const int   src = (lane + 63) & 63;

        // t = 0 init: alpha[0]=q0[blank], alpha[1]=q0[yt[0]], rest 0.
        float a0 = l0 ? qblank[0]           : 0.0f;  // even state 2*lane
        float a1 = l0 ? (float)qtab[0][lane] : 0.0f; // odd state 2*lane+1
        float aX = 0.0f;                              // state 128 (lane 0 only)
        int Esum = 0;

        float qb = qblank[1];
        float ql = (float)qtab[1][lane];
        #pragma unroll 8
        for (int t = 1; t < TT; ++t) {
            float qb_n = 0.0f, ql_n = 0.0f;
            if (t + 1 < TT) { qb_n = qblank[t + 1]; ql_n = (float)qtab[t + 1][lane]; }
            float nb = __shfl(a1, src);     // alpha[2*lane-1]; lane0 gets alpha[127]
            float nb0 = l0 ? 0.0f : nb;
            float na0 = (a0 + nb0) * qb;                // blank state: no skip
            float na1 = fmaf(mskip, nb, a0 + a1) * ql;  // label state: optional skip
            aX = l0 ? (aX + nb) * qb : 0.0f;            // state 128 (blank)
            a0 = na0; a1 = na1;
            if ((t & 7) == 7) {                         // power-of-2 rescale
                float m = fmaxf(a0, a1);
                m = fmaxf(m, l0 ? aX : 0.0f);
                #pragma unroll
                for (int off = 1; off < 64; off <<= 1) m = fmaxf(m, __shfl_xor(m, off));
                int ex = (int)((__float_as_uint(m) >> 23) & 0xFF);
                int e  = 127 - ex;
                float sc = __uint_as_float((unsigned)(127 + e) << 23);
                a0 *= sc; a1 *= sc; aX *= sc;
                Esum += e;
            }
            qb = qb_n; ql = ql_n;
        }
        float a127 = __shfl(a1, 63);
        if (lane == 0) {
            float tot = aX + a127;          // alpha[128] + alpha[127]
            out[b] = logZ + (float)Esum * 0.69314718055994531f - __logf(tot);
        }
    }
}

extern "C" void kernel_launch(void* const* d_in, const int* in_sizes, int n_in,
                              void* d_out, int out_size, void* d_ws, size_t ws_size,
                              hipStream_t stream) {
    const int*   y_true = (const int*)d_in[0];
    const float* y_pred = (const float*)d_in[1];
    float*       out    = (float*)d_out;
    ctc_fwd_kernel<<<BATCH, 256, 0, stream>>>(y_true, y_pred, out);
}

// Round 4
// 42.340 us; speedup vs baseline: 4.1290x; 1.2928x over previous
//
#include <hip/hip_runtime.h>
#include <math.h>

// CTC forward loss, Keras ctc_batch_cost semantics.
// B=1024, T=256, C=128, L=64, S=2L+1=129, blank=C-1=127.
// Prob-domain forward DP (no per-step transcendentals) with power-of-2
// rescaling every 8 steps. Phase A: 4 waves stream y_pred, row-sum via DPP
// reduce (VALU, no LDS unit), label gather via 2 ds_bpermute, fp16 q-table.
// Phase B: single wave, states in registers, neighbor pass via DPP wave_rol:1.
#define BATCH 1024
#define TT    256
#define CC    128
#define LL    64
#define BLANK 127
#define EPSV  (1e-7f)

typedef _Float16 half_t;

// DPP helpers (gfx9/CDNA encodings): row_shr:N = 0x110+N, row_bcast:15 = 0x142,
// row_bcast:31 = 0x143, wave_rol:1 = 0x134.
template <int CTRL>
__device__ __forceinline__ float dpp0(float x) {   // invalid lanes -> 0
    return __int_as_float(__builtin_amdgcn_update_dpp(
        0, __float_as_int(x), CTRL, 0xF, 0xF, true));
}
template <int CTRL>
__device__ __forceinline__ float dppS(float x) {   // invalid lanes -> self
    return __int_as_float(__builtin_amdgcn_update_dpp(
        __float_as_int(x), __float_as_int(x), CTRL, 0xF, 0xF, false));
}
__device__ __forceinline__ float wave_sum63(float s) {  // total lands in lane 63
    s += dpp0<0x111>(s);
    s += dpp0<0x112>(s);
    s += dpp0<0x114>(s);
    s += dpp0<0x118>(s);
    s += dpp0<0x142>(s);
    s += dpp0<0x143>(s);
    return s;
}
__device__ __forceinline__ float wave_max_bcast(float m) {  // max, broadcast to all
    m = fmaxf(m, dppS<0x111>(m));
    m = fmaxf(m, dppS<0x112>(m));
    m = fmaxf(m, dppS<0x114>(m));
    m = fmaxf(m, dppS<0x118>(m));
    m = fmaxf(m, dppS<0x142>(m));
    m = fmaxf(m, dppS<0x143>(m));
    return __int_as_float(__builtin_amdgcn_readlane(__float_as_int(m), 63));
}
__device__ __forceinline__ float rol1(float x) {    // lane i <- lane (i-1)&63
    return __int_as_float(__builtin_amdgcn_update_dpp(
        __float_as_int(x), __float_as_int(x), 0x134, 0xF, 0xF, false));
}

__global__ __launch_bounds__(256) void ctc_fwd_kernel(const int* __restrict__ y_true,
                                                      const float* __restrict__ y_pred,
                                                      float* __restrict__ out) {
    __shared__ half_t qtab[TT][66];   // q[t][label slot l] = p[t][yt[l]]+eps
    __shared__ float  qblank[TT];     // q[t][blank]
    __shared__ float  logZpart[4];
    __shared__ int    labels[LL];

    const int b    = blockIdx.x;
    const int tid  = threadIdx.x;
    const int wv   = tid >> 6;
    const int lane = tid & 63;

    const float* yp = y_pred + (size_t)b * (TT * CC);

    if (tid < LL) labels[tid] = y_true[b * LL + tid];
    __syncthreads();

    const int lab  = labels[lane];
    const int srcl = lab >> 1;

    // ---------------- Phase A: stream y_pred, build qtab/qblank/logZ ----------------
    // Wave w handles rows t = w + 4*i; unroll 8 (8 loads in flight, 8 chains).
    float zacc = 0.0f;                 // meaningful on lane 63 only
    float2 v[8];
    #pragma unroll
    for (int j = 0; j < 8; ++j)
        v[j] = ((const float2*)(yp + (size_t)(wv + 4 * j) * CC))[lane];

    for (int k = 0; k < 8; ++k) {
        float2 vn[8];
        if (k < 7) {
            #pragma unroll
            for (int j = 0; j < 8; ++j)
                vn[j] = ((const float2*)(yp + (size_t)(wv + 32 * (k + 1) + 4 * j) * CC))[lane];
        }
        #pragma unroll
        for (int j = 0; j < 8; ++j) {
            const int t = wv + 32 * k + 4 * j;
            float q0 = v[j].x + EPSV, q1 = v[j].y + EPSV;
            float s = wave_sum63(q0 + q1);
            zacc += __logf(s);         // garbage off lane 63, but finite (s>0)
            // label gather: col 2*srcl = q0 of lane srcl, col 2*srcl+1 = q1
            float ga = __shfl(q0, srcl);
            float gb = __shfl(q1, srcl);
            qtab[t][lane] = (half_t)((lab & 1) ? gb : ga);
            if (lane == 63) qblank[t] = q1;   // col 127 == blank
        }
        #pragma unroll
        for (int j = 0; j < 8; ++j) v[j] = vn[j];
    }
    if (lane == 63) logZpart[wv] = zacc;
    __syncthreads();

    // ---------------- Phase B: single-wave register DP ----------------
    if (wv == 0) {
        const float logZ = logZpart[0] + logZpart[1] + logZpart[2] + logZpart[3];
        const int   labm1 = labels[(lane + 63) & 63];
        const float mskip = (lane >= 1 && lab != labm1) ? 1.0f : 0.0f;
        const bool  l0 = (lane == 0);

        // t = 0 init: alpha[0]=q0[blank], alpha[1]=q0[yt[0]], rest 0.
        float a0 = l0 ? qblank[0]            : 0.0f;  // even state 2*lane
        float a1 = l0 ? (float)qtab[0][lane] : 0.0f;  // odd state 2*lane+1
        float aX = 0.0f;                               // state 128 (lane 0 only)
        int Esum = 0;

        float qb = qblank[1];
        float ql = (float)qtab[1][lane];
        #pragma unroll 8
        for (int t = 1; t < TT; ++t) {
            float qb_n = 0.0f, ql_n = 0.0f;
            if (t + 1 < TT) { qb_n = qblank[t + 1]; ql_n = (float)qtab[t + 1][lane]; }
            float nb = rol1(a1);            // alpha[2*lane-1]; lane0 gets alpha[127]
            float nb0 = l0 ? 0.0f : nb;
            float na0 = (a0 + nb0) * qb;                // blank state: no skip
            float na1 = fmaf(mskip, nb, a0 + a1) * ql;  // label state: optional skip
            aX = l0 ? (aX + nb) * qb : 0.0f;            // state 128 (blank)
            a0 = na0; a1 = na1;
            if ((t & 7) == 7) {                         // power-of-2 rescale
                float m = fmaxf(a0, a1);
                m = fmaxf(m, l0 ? aX : 0.0f);
                float mall = wave_max_bcast(m);
                int ex = (int)((__float_as_uint(mall) >> 23) & 0xFF);
                int e  = 127 - ex;
                float sc = __uint_as_float((unsigned)(127 + e) << 23);
                a0 *= sc; a1 *= sc; aX *= sc;
                Esum += e;
            }
            qb = qb_n; ql = ql_n;
        }
        float a127 = __builtin_amdgcn_readlane(__float_as_int(a1), 63) != 0
                     ? __int_as_float(__builtin_amdgcn_readlane(__float_as_int(a1), 63))
                     : 0.0f;
        if (lane == 0) {
            float tot = aX + a127;          // alpha[128] + alpha[127]
            out[b] = logZ + (float)Esum * 0.69314718055994531f - __logf(tot);
        }
    }
}

extern "C" void kernel_launch(void* const* d_in, const int* in_sizes, int n_in,
                              void* d_out, int out_size, void* d_ws, size_t ws_size,
                              hipStream_t stream) {
    const int*   y_true = (const int*)d_in[0];
    const float* y_pred = (const float*)d_in[1];
    float*       out    = (float*)d_out;
    ctc_fwd_kernel<<<BATCH, 256, 0, stream>>>(y_true, y_pred, out);
}

// Round 5
// 37.381 us; speedup vs baseline: 4.6767x; 1.1327x over previous
//
#include <hip/hip_runtime.h>
#include <math.h>

// CTC forward loss, Keras ctc_batch_cost semantics.
// B=1024, T=256, C=128, L=64, S=2L+1=129, blank=C-1=127.
// Prob-domain forward DP (no per-step transcendentals), power-of-2 rescale
// once per 8-step chunk. Phase A: 8 waves stream y_pred as float4 (2 rows
// per load), row sums via DPP half-wave reduce, label gather via packed-fp16
// register shuffles, build fp16 q-table in LDS. Phase B: single wave runs
// the DP in registers with chunk-ahead LDS prefetch.
#define BATCH 1024
#define TT    256
#define CC    128
#define LL    64
#define EPSV  (1e-7f)

typedef float f32x4 __attribute__((ext_vector_type(4)));

// DPP ctrl: row_shr:N = 0x110+N, row_bcast:15 = 0x142, row_bcast:31 = 0x143,
// wave_rol:1 = 0x134.
template <int CTRL>
__device__ __forceinline__ float dpp0(float x) {   // invalid lanes -> 0
    return __int_as_float(__builtin_amdgcn_update_dpp(0, __float_as_int(x), CTRL, 0xF, 0xF, true));
}
template <int CTRL>
__device__ __forceinline__ float dppS(float x) {   // invalid lanes -> self
    return __int_as_float(__builtin_amdgcn_update_dpp(__float_as_int(x), __float_as_int(x), CTRL, 0xF, 0xF, false));
}
__device__ __forceinline__ float rol1_f(float x) { // lane i <- lane (i-1)&63
    return __int_as_float(__builtin_amdgcn_update_dpp(__float_as_int(x), __float_as_int(x), 0x134, 0xF, 0xF, false));
}
__device__ __forceinline__ int rol1_i(int x) {
    return __builtin_amdgcn_update_dpp(x, x, 0x134, 0xF, 0xF, false);
}
__device__ __forceinline__ float rdlane(float x, int l) {
    return __int_as_float(__builtin_amdgcn_readlane(__float_as_int(x), l));
}
__device__ __forceinline__ float wave_max_bcast(float m) {
    m = fmaxf(m, dppS<0x111>(m));
    m = fmaxf(m, dppS<0x112>(m));
    m = fmaxf(m, dppS<0x114>(m));
    m = fmaxf(m, dppS<0x118>(m));
    m = fmaxf(m, dppS<0x142>(m));
    m = fmaxf(m, dppS<0x143>(m));
    return rdlane(m, 63);
}
__device__ __forceinline__ unsigned f2h(float x) { // fp32 -> fp16 bit pattern (RTN)
    _Float16 h = (_Float16)x;
    unsigned short u; __builtin_memcpy(&u, &h, 2);
    return (unsigned)u;
}
__device__ __forceinline__ float h2f(unsigned short u) {
    _Float16 h; __builtin_memcpy(&h, &u, 2);
    return (float)h;
}

__global__ __launch_bounds__(512, 8) void ctc_fwd_kernel(const int* __restrict__ y_true,
                                                         const float* __restrict__ y_pred,
                                                         float* __restrict__ out) {
    __shared__ unsigned short qtab[TT][66];  // q[t][l] = p[t][yt[l]]+eps (fp16 bits)
    __shared__ float qblank[TT];             // q[t][blank]
    __shared__ float logZpart[8];

    const int b    = blockIdx.x;
    const int tid  = threadIdx.x;
    const int wv   = tid >> 6;
    const int lane = tid & 63;

    const float* yp = y_pred + (size_t)b * (TT * CC);
    const int lab  = y_true[b * LL + lane];  // lane l holds label l (l<64)
    const int srcA = lab >> 2;               // source lane for row part A
    const int srcB = 32 + srcA;              // ... row part B
    const bool hiPair = (lab & 2) != 0;
    const bool hiHalf = (lab & 1) != 0;

    // float4 covers 2 rows: lanes 0-31 -> row 2*r2 cols 4L..4L+3, lanes 32-63 -> row 2*r2+1.
    const int off = ((lane >> 5) << 7) + ((lane & 31) << 2);
    const float* base = yp + off;

    // ---------------- Phase A: wave wv handles row-pairs r2 = wv + 8*i, i=0..15 ----------------
    float zacc = 0.0f;                       // meaningful on lanes 31 (rows A) and 63 (rows B)
    f32x4 v[4];
    #pragma unroll
    for (int j = 0; j < 4; ++j)
        v[j] = __builtin_nontemporal_load((const f32x4*)(base + 256 * (wv + 8 * j)));

    for (int g = 0; g < 4; ++g) {
        f32x4 vn[4];
        if (g < 3) {
            #pragma unroll
            for (int j = 0; j < 4; ++j)
                vn[j] = __builtin_nontemporal_load((const f32x4*)(base + 256 * (wv + 32 * (g + 1) + 8 * j)));
        }
        #pragma unroll
        for (int j = 0; j < 4; ++j) {
            const int r2 = wv + 32 * g + 8 * j;
            const int tA = 2 * r2, tB = tA + 1;
            float q0 = v[j][0] + EPSV, q1 = v[j][1] + EPSV;
            float q2 = v[j][2] + EPSV, q3 = v[j][3] + EPSV;
            // half-wave reduce: row-A total -> lane 31, row-B total -> lane 63
            float s = (q0 + q1) + (q2 + q3);
            s += dpp0<0x111>(s);
            s += dpp0<0x112>(s);
            s += dpp0<0x114>(s);
            s += dpp0<0x118>(s);
            s += dpp0<0x142>(s);
            zacc += __logf(s);               // garbage off lanes 31/63 (finite)
            // pack own 4 cols to fp16 pairs, gather via register shuffles
            int i01 = (int)(f2h(q0) | (f2h(q1) << 16));
            int i23 = (int)(f2h(q2) | (f2h(q3) << 16));
            int gA01 = __shfl(i01, srcA), gA23 = __shfl(i23, srcA);
            int gB01 = __shfl(i01, srcB), gB23 = __shfl(i23, srcB);
            int sA = hiPair ? gA23 : gA01;
            int sB = hiPair ? gB23 : gB01;
            qtab[tA][lane] = (unsigned short)(hiHalf ? ((unsigned)sA >> 16) : (sA & 0xFFFF));
            qtab[tB][lane] = (unsigned short)(hiHalf ? ((unsigned)sB >> 16) : (sB & 0xFFFF));
            if ((lane & 31) == 31) qblank[tA + (lane >> 5)] = q3;   // col 127 == blank
        }
        #pragma unroll
        for (int j = 0; j < 4; ++j) v[j] = vn[j];
    }
    {
        float z31 = rdlane(zacc, 31), z63 = rdlane(zacc, 63);
        if (lane == 0) logZpart[wv] = z31 + z63;
    }
    __syncthreads();

    // ---------------- Phase B: single-wave register DP ----------------
    if (wv == 0) {
        float logZ = 0.0f;
        #pragma unroll
        for (int w = 0; w < 8; ++w) logZ += logZpart[w];

        const int labm1  = rol1_i(lab);
        const float mskip = (lane >= 1 && lab != labm1) ? 1.0f : 0.0f;
        const bool l0 = (lane == 0);

        // t=0 init: alpha[0]=q0[blank], alpha[1]=q0[yt[0]], rest 0.
        float a0 = l0 ? qblank[0] : 0.0f;           // even state 2*lane
        float a1 = l0 ? h2f(qtab[0][lane]) : 0.0f;  // odd state 2*lane+1
        float aX = 0.0f;                             // state 128 (lane 0 only)
        int Esum = 0;

        float qbv[8], qlv[8];
        #pragma unroll
        for (int i = 0; i < 8; ++i) {               // preload t = 1..8
            qbv[i] = qblank[1 + i];
            qlv[i] = h2f(qtab[1 + i][lane]);
        }

        for (int t0 = 1; t0 + 8 <= TT; t0 += 8) {   // 31 full chunks: t = 1..248
            float qbn[8], qln[8];
            #pragma unroll
            for (int i = 0; i < 8; ++i) {           // prefetch next chunk (clamped)
                int tn = t0 + 8 + i; tn = (tn < TT) ? tn : (TT - 1);
                qbn[i] = qblank[tn];
                qln[i] = h2f(qtab[tn][lane]);
            }
            #pragma unroll
            for (int i = 0; i < 8; ++i) {
                float nb  = rol1_f(a1);             // alpha[2*lane-1]; lane0 gets alpha[127]
                float na0 = (a0 + (l0 ? 0.0f : nb)) * qbv[i];
                float na1 = fmaf(mskip, nb, a0 + a1) * qlv[i];
                aX = l0 ? (aX + nb) * qbv[i] : 0.0f;
                a0 = na0; a1 = na1;
            }
            // power-of-2 rescale once per chunk
            float m = fmaxf(fmaxf(a0, a1), aX);
            float mall = wave_max_bcast(m);
            int ex = (int)((__float_as_uint(mall) >> 23) & 0xFF);
            int e  = 127 - ex;
            float sc = __uint_as_float((unsigned)(127 + e) << 23);
            a0 *= sc; a1 *= sc; aX *= sc;
            Esum += e;
            #pragma unroll
            for (int i = 0; i < 8; ++i) { qbv[i] = qbn[i]; qlv[i] = qln[i]; }
        }
        // epilogue: t = 249..255 (qbv[0..6] hold them)
        #pragma unroll
        for (int i = 0; i < 7; ++i) {
            float nb  = rol1_f(a1);
            float na0 = (a0 + (l0 ? 0.0f : nb)) * qbv[i];
            float na1 = fmaf(mskip, nb, a0 + a1) * qlv[i];
            aX = l0 ? (aX + nb) * qbv[i] : 0.0f;
            a0 = na0; a1 = na1;
        }
        float a127 = rdlane(a1, 63);
        if (lane == 0) {
            float tot = aX + a127;                  // alpha[128] + alpha[127]
            out[b] = logZ + (float)Esum * 0.69314718055994531f - __logf(tot);
        }
    }
}

extern "C" void kernel_launch(void* const* d_in, const int* in_sizes, int n_in,
                              void* d_out, int out_size, void* d_ws, size_t ws_size,
                              hipStream_t stream) {
    const int*   y_true = (const int*)d_in[0];
    const float* y_pred = (const float*)d_in[1];
    float*       out    = (float*)d_out;
    ctc_fwd_kernel<<<BATCH, 512, 0, stream>>>(y_true, y_pred, out);
}